// Round 7
// baseline (382.641 us; speedup 1.0000x reference)
//
#include <hip/hip_runtime.h>

// L2_Self_Attn flattened pipeline for MI355X (gfx950).
// B=4, C=128, H=W=64, N=4096. All reshapes are flat-view reinterpretations.
// Attention branch is suppressed by gamma/bound ~6e-6 -> bf16 everywhere in it.
//
// Pipeline (5 kernels):
//  prep   : scale = gamma/bound, WqT (f32, for k1a), Wqb/Wvb (bf16 weights)
//  k1a    : Q = conv1x1(x,Wq,bq) -> Qb bf16 [B][N][C]; biasg = s*||q_n||^2
//  k1b    : Vt bf16 [B][C][N]
//  k2     : flash attention (16 q-rows/wave, 4-way key split, swapped QK^T,
//           XOR-swizzled P, tree merge) -> F0b16 bf16 [B][N][C]
//  g_fused: per 128x128 pixel-tile, 3 chained MFMA GEMMs:
//           T1[o][jj]=Wq@X0+bq ; T2[p][o]=s2*T1@Wq^T ; out=scale*(Wv@T2+bv)+x
//           (Vc/Vn view duality: j-tile width 128 aligned -> complete Vn rows)

typedef __attribute__((ext_vector_type(4))) float f32x4;
typedef __attribute__((ext_vector_type(2))) float f32x2;
typedef __attribute__((ext_vector_type(8))) short s16x8;

#define SCALE_S  0.08838834764831845f   // 1/sqrt(128)
#define SCALE_2S 0.17677669529663689f   // 2/sqrt(128)

__device__ __forceinline__ ushort f2bf(float f){
  uint u = __float_as_uint(f);
  u += 0x7fffu + ((u >> 16) & 1u);      // RTNE
  return (ushort)(u >> 16);
}
__device__ __forceinline__ uint packbf(float lo, float hi){
  return (uint)f2bf(lo) | ((uint)f2bf(hi) << 16);
}

// grid(2): block0 = norms+scale+Wqb+Wvb, block1 = WqT (LDS-tiled transpose).
__global__ __launch_bounds__(256) void prep_kernel(const float* __restrict__ Wq, const float* __restrict__ Wv,
                                                   const float* __restrict__ gamma,
                                                   float* __restrict__ WqT, ushort* __restrict__ Wqb,
                                                   ushort* __restrict__ Wvb, float* __restrict__ scale){
  __shared__ float tile[32][33];
  __shared__ float red[256];
  int t = threadIdx.x;
  if (blockIdx.x == 0){
    float sq = 0.f, sv = 0.f;
    for (int i = t*4; i < 16384; i += 1024){
      f32x4 a = *(const f32x4*)(Wq + i);
      f32x4 b = *(const f32x4*)(Wv + i);
      #pragma unroll
      for (int e=0; e<4; e++){
        sq += a[e]*a[e]; sv += b[e]*b[e];
        Wqb[i+e] = f2bf(a[e]);
        Wvb[i+e] = f2bf(b[e]);
      }
    }
    red[t] = sq; __syncthreads();
    for (int s = 128; s > 0; s >>= 1){ if (t < s) red[t] += red[t+s]; __syncthreads(); }
    sq = red[0]; __syncthreads();
    red[t] = sv; __syncthreads();
    for (int s = 128; s > 0; s >>= 1){ if (t < s) red[t] += red[t+s]; __syncthreads(); }
    sv = red[0];
    if (t == 0){
      const double PHI = 5.5957572195283385;                 // LambertW(4096/e)
      double A = sqrt(32.0) * (4.0*PHI + 1.0);               // sqrt(N/C)*(4*phi+1)
      float bound = (float)(A * sqrt((double)sq) * sqrt((double)sv));
      scale[0] = gamma[0] / bound;
    }
  } else {
    int r = t >> 3, cq = (t & 7) * 4;
    for (int tt = 0; tt < 16; tt++){
      int tr = tt >> 2, tc = tt & 3;
      __syncthreads();
      f32x4 v = *(const f32x4*)(Wq + (tr*32 + r)*128 + tc*32 + cq);
      #pragma unroll
      for (int e=0; e<4; e++) tile[r][cq+e] = v[e];
      __syncthreads();
      f32x4 o;
      #pragma unroll
      for (int e=0; e<4; e++) o[e] = tile[cq+e][r];
      *(f32x4*)(WqT + (tc*32 + r)*128 + tr*32 + cq) = o;
    }
  }
}

// Q-conv + nq. grid (256,4), block 256.
__global__ __launch_bounds__(256) void k1a_qconv(const float* __restrict__ x, const float* __restrict__ WqT,
                                                 const float* __restrict__ bq,
                                                 ushort* __restrict__ Qb, float* __restrict__ biasg){
  __shared__ float nq_part[2][8][2];
  int b = blockIdx.y;
  int n0 = blockIdx.x * 16;
  int c  = threadIdx.x & 127;
  int ng = threadIdx.x >> 7;
  int lane = threadIdx.x & 63;
  int wave = threadIdx.x >> 6;
  const float* xb = x + (size_t)b*524288 + n0 + ng*8;
  float a[8];
  float bias0 = bq[c];
  #pragma unroll
  for (int u=0; u<8; u++) a[u] = bias0;
  for (int i=0; i<128; i++){
    float w = WqT[i*128 + c];
    const float* xr = xb + (size_t)i*4096;
    f32x4 x0 = *(const f32x4*)xr;
    f32x4 x1 = *(const f32x4*)(xr + 4);
    #pragma unroll
    for (int u=0; u<4; u++){
      a[u]   = fmaf(w, x0[u], a[u]);
      a[u+4] = fmaf(w, x1[u], a[u+4]);
    }
  }
  ushort* qb = Qb + (size_t)(b*4096 + n0 + ng*8)*128 + c;
  #pragma unroll
  for (int u=0; u<8; u++) qb[u*128] = f2bf(a[u]);
  #pragma unroll
  for (int u=0; u<8; u++){
    float v = a[u]*a[u];
    #pragma unroll
    for (int d=1; d<64; d<<=1) v += __shfl_xor(v, d, 64);
    if (lane == 0) nq_part[ng][u][wave & 1] = v;
  }
  __syncthreads();
  if (threadIdx.x < 16){
    int g = threadIdx.x >> 3, u = threadIdx.x & 7;
    biasg[b*4096 + n0 + g*8 + u] = SCALE_S * (nq_part[g][u][0] + nq_part[g][u][1]);
  }
}

// Vt[b][c][m] = bf16(x_flat[b][m*128+c]). grid (64,4), block 256.
__global__ __launch_bounds__(256) void k1b_vt(const float* __restrict__ x, ushort* __restrict__ Vt){
  __shared__ __align__(16) ushort t[128*72];
  int b = blockIdx.y; int m0 = blockIdx.x*64;
  const float* xb = x + (size_t)b*524288 + (size_t)m0*128;
  for (int u = threadIdx.x; u < 64*32; u += 256){
    int m = u >> 5, seg = u & 31;
    f32x4 v = *(const f32x4*)(xb + m*128 + seg*4);
    #pragma unroll
    for (int e=0; e<4; e++) t[(seg*4+e)*72 + m] = f2bf(v[e]);
  }
  __syncthreads();
  ushort* vtb = Vt + (size_t)b*524288 + m0;
  for (int u = threadIdx.x; u < 128*8; u += 256){
    int c = u >> 3, seg = u & 7;
    *(s16x8*)(vtb + (size_t)c*4096 + seg*8) = *(const s16x8*)&t[c*72 + seg*8];
  }
}

// Flash attention. 1-D grid 1024 (XCD-swizzled), block 256 = 4 waves.
// Each wave: 16 q-rows, keys [wave*1024,(wave+1)*1024), kt=16. Swapped QK^T.
// Output: F0b16 bf16 [B][N][C]. LDS 16640 B.
__global__ __launch_bounds__(256, 3) void k2_flash(const ushort* __restrict__ Qb, const ushort* __restrict__ Vt,
                                                   const float* __restrict__ biasg, ushort* __restrict__ F0b16){
  extern __shared__ __align__(16) char smem[];
  int bid = blockIdx.x;
  int xs = bid & 7, jj = bid >> 3;
  int b  = xs >> 1;                       // batch -> XCD pair (L2-resident K/V)
  int q0 = ((xs & 1) * 128 + jj) * 16;    // 256 q-tiles per batch

  int tid = threadIdx.x;
  int wave = tid >> 6, lane = tid & 63;
  int l15 = lane & 15, l4 = lane >> 4;
  const ushort* Qbb = Qb + (size_t)b*524288;
  const ushort* Vtb = Vt + (size_t)b*524288;
  const float*  bb  = biasg + (size_t)b*4096;
  char* Pb = smem + wave*2048;            // per-wave P buffer: 16 rows x 128B

  s16x8 qf[4];
  #pragma unroll
  for (int ks=0; ks<4; ks++)
    qf[ks] = *(const s16x8*)(Qbb + (size_t)(q0 + l15)*128 + ks*32 + l4*8);

  f32x4 acc[8];
  #pragma unroll
  for (int ct=0; ct<8; ct++) acc[ct] = (f32x4){0.f,0.f,0.f,0.f};
  float mrun = -1e30f, lrun = 0.f;        // per lane: state of query l15

  int sw = (l15 & 7) << 4;

  for (int kt=0; kt<16; kt++){
    int m0 = wave*1024 + kt*64;
    f32x4 bv[4];
    #pragma unroll
    for (int mt=0; mt<4; mt++)
      bv[mt] = *(const f32x4*)(bb + m0 + mt*16 + l4*4);

    f32x4 sa[4];
    #pragma unroll
    for (int mt=0; mt<4; mt++) sa[mt] = (f32x4){0.f,0.f,0.f,0.f};
    #pragma unroll
    for (int ks=0; ks<4; ks++){
      s16x8 kb[4];
      #pragma unroll
      for (int mt=0; mt<4; mt++)
        kb[mt] = *(const s16x8*)(Qbb + (size_t)(m0 + mt*16 + l15)*128 + ks*32 + l4*8);
      #pragma unroll
      for (int mt=0; mt<4; mt++)
        sa[mt] = __builtin_amdgcn_mfma_f32_16x16x32_bf16(kb[mt], qf[ks], sa[mt], 0, 0, 0);
    }
    #pragma unroll
    for (int mt=0; mt<4; mt++)
      #pragma unroll
      for (int r=0; r<4; r++)
        sa[mt][r] = fmaf(SCALE_2S, sa[mt][r], -bv[mt][r]);
    float m16 = sa[0][0];
    #pragma unroll
    for (int mt=0; mt<4; mt++)
      #pragma unroll
      for (int r=0; r<4; r++) m16 = fmaxf(m16, sa[mt][r]);
    m16 = fmaxf(m16, __shfl_xor(m16, 16, 64));
    m16 = fmaxf(m16, __shfl_xor(m16, 32, 64));
    int need = __any(m16 > mrun);
    float mn = fmaxf(mrun, m16);
    float corr = 1.0f;
    if (need){ corr = __expf(mrun - mn); mrun = mn; }
    float rs = 0.f;
    #pragma unroll
    for (int mt=0; mt<4; mt++){
      #pragma unroll
      for (int r=0; r<4; r++){
        float p = __expf(sa[mt][r] - mn);
        sa[mt][r] = p;
        rs += p;
      }
      uint2 w2;
      w2.x = packbf(sa[mt][0], sa[mt][1]);
      w2.y = packbf(sa[mt][2], sa[mt][3]);
      *(uint2*)(Pb + ((l15*128 + mt*32 + l4*8) ^ sw)) = w2;
    }
    rs += __shfl_xor(rs, 16, 64);
    rs += __shfl_xor(rs, 32, 64);
    lrun = lrun*corr + rs;
    if (need){
      float cA[4];
      #pragma unroll
      for (int r=0; r<4; r++) cA[r] = __shfl(corr, l4*4 + r, 64);
      #pragma unroll
      for (int ct=0; ct<8; ct++)
        #pragma unroll
        for (int r=0; r<4; r++) acc[ct][r] *= cA[r];
    }
    #pragma unroll
    for (int ks2=0; ks2<2; ks2++){
      s16x8 pa = *(const s16x8*)(Pb + ((l15*128 + ks2*64 + l4*16) ^ sw));
      #pragma unroll
      for (int ct=0; ct<8; ct++){
        s16x8 vb = *(const s16x8*)(Vtb + (size_t)(ct*16 + l15)*4096 + m0 + ks2*32 + l4*8);
        acc[ct] = __builtin_amdgcn_mfma_f32_16x16x32_bf16(pa, vb, acc[ct], 0, 0, 0);
      }
    }
  }

  // ---- tree merge of 4 key-split states (16 rows) ----
  float* macc = (float*)smem;             // [2][16][128] (aliases P bufs)
  f32x2* ml   = (f32x2*)(smem + 16384);   // [2][16]
  __syncthreads();
  if (wave >= 2){
    int wi = wave - 2;
    #pragma unroll
    for (int ct=0; ct<8; ct++)
      #pragma unroll
      for (int r=0; r<4; r++)
        macc[wi*2048 + (l4*4 + r)*128 + ct*16 + l15] = acc[ct][r];
    if (lane < 16) ml[wi*16 + lane] = (f32x2){mrun, lrun};
  }
  __syncthreads();
  float mA[4], lA[4];
  if (wave < 2){
    int wi = wave;
    #pragma unroll
    for (int r=0; r<4; r++){
      mA[r] = __shfl(mrun, l4*4 + r, 64);
      lA[r] = __shfl(lrun, l4*4 + r, 64);
      f32x2 pm = ml[wi*16 + l4*4 + r];
      float ms = fmaxf(mA[r], pm.x);
      float aA = __expf(mA[r] - ms);
      float aB = __expf(pm.x - ms);
      lA[r] = aA*lA[r] + aB*pm.y;
      mA[r] = ms;
      #pragma unroll
      for (int ct=0; ct<8; ct++)
        acc[ct][r] = aA*acc[ct][r] + aB*macc[wi*2048 + (l4*4 + r)*128 + ct*16 + l15];
    }
  }
  __syncthreads();
  if (wave == 1){
    #pragma unroll
    for (int ct=0; ct<8; ct++)
      #pragma unroll
      for (int r=0; r<4; r++)
        macc[(l4*4 + r)*128 + ct*16 + l15] = acc[ct][r];
    if (l15 == 0){
      #pragma unroll
      for (int r=0; r<4; r++)
        ml[l4*4 + r] = (f32x2){mA[r], lA[r]};
    }
  }
  __syncthreads();
  if (wave == 0){
    ushort* Fb = F0b16 + (size_t)b*524288;
    #pragma unroll
    for (int r=0; r<4; r++){
      f32x2 pm = ml[l4*4 + r];
      float ms = fmaxf(mA[r], pm.x);
      float aA = __expf(mA[r] - ms);
      float aB = __expf(pm.x - ms);
      float inv = 1.0f / (aA*lA[r] + aB*pm.y);
      #pragma unroll
      for (int ct=0; ct<8; ct++){
        float ob = macc[(l4*4 + r)*128 + ct*16 + l15];
        Fb[(size_t)(q0 + l4*4 + r)*128 + ct*16 + l15] = f2bf((aA*acc[ct][r] + aB*ob) * inv);
      }
    }
  }
}

// Fused epilogue: grid 128 (XCD-swizzled), block 512 = 8 waves, one 128x128
// pixel-tile (j0 = t*128). Chain (all 16x16x32 bf16 MFMA, k-maps cancel):
//  stage: X0T[jj][i] (LDS pad-136) from F0b16 Vn rows (i*32+t)
//  G1: D1[jj][o] = mfma(A=X0T rows, B=Wqb rows); +bq[o]; packed-> T1[o][jj]
//  G2: D2[o][p]  = mfma(A=T1 rows,  B=Wqb rows); *s2;   packed-> T2[p][o]
//  G3: D3[o2][p] = mfma(A=Wvb rows, B=T2 rows); out = sc*(D3+bv[o2]) + x
// LDS: X0T @0 (34816) | T1 @34816 (32768) | T2 @0 (aliases X0T, dead after G1)
__global__ __launch_bounds__(512) void g_fused(const ushort* __restrict__ F0b16, const ushort* __restrict__ Wqb,
                                               const ushort* __restrict__ Wvb, const float* __restrict__ bq,
                                               const float* __restrict__ bv, const float* __restrict__ x,
                                               const float* __restrict__ scale, float* __restrict__ out){
  extern __shared__ __align__(16) char smem[];
  ushort* X0T = (ushort*)smem;            // [128][136]
  char*   T1  = smem + 34816;             // [o][jj] bf16, 256B rows, XOR swz
  char*   T2  = smem;                     // [p][o]  bf16 (aliases X0T)
  int bid = blockIdx.x;
  int xs = bid & 7;
  int b = xs >> 1;
  int t = (xs & 1)*16 + (bid >> 3);       // 32 j-tiles per batch
  int tid = threadIdx.x;
  int wave = tid >> 6, lane = tid & 63;
  int l15 = lane & 15, l4 = lane >> 4;
  int m0 = wave * 16;
  int sw = (l15 & 7) << 4;
  const ushort* F0bb = F0b16 + (size_t)b*524288;

  // stage X0T[jj][i] from F0 rows (i*32+t): coalesced 256B loads per 4 lanes
  {
    int i = tid >> 2, c4 = (tid & 3) * 32;
    const ushort* src = F0bb + (size_t)(i*32 + t)*128 + c4;
    #pragma unroll
    for (int h=0; h<4; h++){
      s16x8 v = *(const s16x8*)(src + h*8);
      #pragma unroll
      for (int e=0; e<8; e++) X0T[(c4 + h*8 + e)*136 + i] = (ushort)v[e];
    }
  }
  __syncthreads();

  f32x4 acc[8];
  // ---- G1: D1[jj][o] ----
  #pragma unroll
  for (int nt=0; nt<8; nt++) acc[nt] = (f32x4){0.f,0.f,0.f,0.f};
  #pragma unroll
  for (int ks=0; ks<4; ks++){
    s16x8 af = *(const s16x8*)(X0T + (size_t)(m0 + l15)*136 + ks*32 + l4*8);
    #pragma unroll
    for (int nt=0; nt<8; nt++){
      s16x8 bf = *(const s16x8*)(Wqb + (size_t)(nt*16 + l15)*128 + ks*32 + l4*8);
      acc[nt] = __builtin_amdgcn_mfma_f32_16x16x32_bf16(af, bf, acc[nt], 0, 0, 0);
    }
  }
  #pragma unroll
  for (int nt=0; nt<8; nt++){
    float bqv = bq[nt*16 + l15];
    uint2 w2;
    w2.x = packbf(acc[nt][0]+bqv, acc[nt][1]+bqv);
    w2.y = packbf(acc[nt][2]+bqv, acc[nt][3]+bqv);
    *(uint2*)(T1 + (((nt*16+l15)*256 + (m0 + l4*4)*2) ^ sw)) = w2;
  }
  __syncthreads();
  // ---- G2: D2[o][p] ----
  #pragma unroll
  for (int nt=0; nt<8; nt++) acc[nt] = (f32x4){0.f,0.f,0.f,0.f};
  #pragma unroll
  for (int ks=0; ks<4; ks++){
    s16x8 af = *(const s16x8*)(T1 + (((m0 + l15)*256 + ks*64 + l4*16) ^ sw));
    #pragma unroll
    for (int nt=0; nt<8; nt++){
      s16x8 bf = *(const s16x8*)(Wqb + (size_t)(nt*16 + l15)*128 + ks*32 + l4*8);
      acc[nt] = __builtin_amdgcn_mfma_f32_16x16x32_bf16(af, bf, acc[nt], 0, 0, 0);
    }
  }
  #pragma unroll
  for (int nt=0; nt<8; nt++){
    uint2 w2;
    w2.x = packbf(acc[nt][0]*SCALE_S, acc[nt][1]*SCALE_S);
    w2.y = packbf(acc[nt][2]*SCALE_S, acc[nt][3]*SCALE_S);
    *(uint2*)(T2 + (((nt*16+l15)*256 + (m0 + l4*4)*2) ^ sw)) = w2;
  }
  __syncthreads();
  // ---- G3: D3[o2][p] + epilogue ----
  #pragma unroll
  for (int nt=0; nt<8; nt++) acc[nt] = (f32x4){0.f,0.f,0.f,0.f};
  #pragma unroll
  for (int ks=0; ks<4; ks++){
    s16x8 af = *(const s16x8*)(Wvb + (size_t)(m0 + l15)*128 + ks*32 + l4*8);
    #pragma unroll
    for (int nt=0; nt<8; nt++){
      s16x8 bf = *(const s16x8*)(T2 + (((nt*16+l15)*256 + ks*64 + l4*16) ^ sw));
      acc[nt] = __builtin_amdgcn_mfma_f32_16x16x32_bf16(af, bf, acc[nt], 0, 0, 0);
    }
  }
  float sc = scale[0];
  f32x4 bvv = *(const f32x4*)(bv + m0 + l4*4);
  const float* xb = x + (size_t)b*524288 + (size_t)(m0 + l4*4)*4096 + t*128 + l15;
  float* ob = out + (size_t)b*524288 + (size_t)(m0 + l4*4)*4096 + t*128 + l15;
  #pragma unroll
  for (int nt=0; nt<8; nt++)
    #pragma unroll
    for (int r=0; r<4; r++)
      ob[r*4096 + nt*16] = fmaf(sc, acc[nt][r] + bvv[r], xb[r*4096 + nt*16]);
}

extern "C" void kernel_launch(void* const* d_in, const int* in_sizes, int n_in,
                              void* d_out, int out_size, void* d_ws, size_t ws_size,
                              hipStream_t stream){
  const float* x     = (const float*)d_in[0];
  const float* Wq    = (const float*)d_in[1];
  const float* bq    = (const float*)d_in[2];
  const float* Wv    = (const float*)d_in[3];
  const float* bv    = (const float*)d_in[4];
  const float* gamma = (const float*)d_in[5];
  char* ws = (char*)d_ws;
  // layout (~12.8 MB): Qb 4M | Vt 4M | biasg 64K | WqT 64K | Wqb 32K | Wvb 32K | scale | F0b16 4M
  ushort* Qb    = (ushort*)(ws + 0);
  ushort* Vt    = (ushort*)(ws + 4194304);
  float*  biasg = (float*)(ws + 8388608);
  float*  WqT   = (float*)(ws + 8454144);
  ushort* Wqb   = (ushort*)(ws + 8519680);
  ushort* Wvb   = (ushort*)(ws + 8552448);
  float*  scale = (float*)(ws + 8585216);
  ushort* F0b16 = (ushort*)(ws + 8585280);
  float*  out   = (float*)d_out;

  prep_kernel<<<2, 256, 0, stream>>>(Wq, Wv, gamma, WqT, Wqb, Wvb, scale);
  k1a_qconv <<<dim3(256,4), 256, 0, stream>>>(x, WqT, bq, Qb, biasg);
  k1b_vt    <<<dim3(64,4),  256, 0, stream>>>(x, Vt);
  k2_flash  <<<1024, 256, 16640, stream>>>(Qb, Vt, biasg, F0b16);
  g_fused   <<<128, 512, 67584, stream>>>(F0b16, Wqb, Wvb, bq, bv, x, scale, out);
}